// Round 4
// baseline (1902.909 us; speedup 1.0000x reference)
//
#include <hip/hip_runtime.h>
#include <hip/hip_bf16.h>

typedef short bf16x8 __attribute__((ext_vector_type(8)));
typedef float f32x4 __attribute__((ext_vector_type(4)));

#define MFMA16(a, b, c) __builtin_amdgcn_mfma_f32_16x16x32_bf16((a), (b), (c), 0, 0, 0)

// log2(e)/32 : folded into q so scores feed v_exp_f32 (2^x) directly
#define QSCALE 0.045084220027780106f

static __device__ __forceinline__ unsigned short f2bf_bits(float f) {
    union { float f; unsigned u; } v; v.f = f;
    unsigned u = v.u;
    u += 0x7fff + ((u >> 16) & 1);   // RNE
    return (unsigned short)(u >> 16);
}
// pack two floats' truncated-bf16 into one dword
static __device__ __forceinline__ unsigned pk_trunc(float lo, float hi) {
    union { float f; unsigned u; } a, b; a.f = lo; b.f = hi;
    return __builtin_amdgcn_perm(b.u, a.u, 0x07060302);
}
// async global->LDS, 16B/lane; LDS addr wave-uniform (HW adds lane*16)
static __device__ __forceinline__ void load_lds16(const void* g, void* s) {
    __builtin_amdgcn_global_load_lds(
        (const __attribute__((address_space(1))) unsigned int*)g,
        (__attribute__((address_space(3))) unsigned int*)s, 16, 0, 0);
}
// 2-bit XOR chunk swizzle for GEMM operand storage (per 32-k window)
static __device__ __forceinline__ size_t gemm_swz(int row, int k, int ld) {
    return (size_t)row * ld + (k & ~31) + ((((k >> 3) & 3) ^ (row & 3)) * 8) + (k & 7);
}
// Fragment-order swizzles for 32-key attention tiles (tile = 2048 elems)
static __device__ __forceinline__ size_t k_swz(int key, int feat) {
    return (size_t)(key >> 5) * 2048 + (size_t)(((((key >> 4) & 1) * 2) + (feat >> 5)) * 512)
         + (key & 15) * 32 + ((feat >> 3) & 3) * 8 + (feat & 7);
}
static __device__ __forceinline__ size_t v_swz(int key, int feat) {
    return (size_t)(key >> 5) * 2048 + (size_t)((feat >> 4) * 512)
         + (feat & 15) * 32 + ((key >> 3) & 3) * 8 + (key & 7);
}

// ---------------- fused prep: weight transposes + rope + rmsnorm ----------------
// blocks [0,1024): w_q->wqkv ; [1024,1280): w_k ; [1280,1536): w_v ;
// [1536,2560): w_o->wo_t ; [2560,3072): rope ; [3072,7168): rmsnorm rows
__global__ __launch_bounds__(256) void prep_kernel(
    const float* __restrict__ x, const float* __restrict__ w_q,
    const float* __restrict__ w_k, const float* __restrict__ w_v,
    const float* __restrict__ w_o, const float* __restrict__ g,
    __hip_bfloat16* __restrict__ xn, __hip_bfloat16* __restrict__ wqkv,
    __hip_bfloat16* __restrict__ wo_t, float* __restrict__ rope)
{
    __shared__ float tile[32][33];
    __shared__ float red[4];
    const int blk = blockIdx.x, tid = threadIdx.x;

    if (blk >= 3072) {  // rmsnorm row
        const int row = blk - 3072;
        const float4 xv = ((const float4*)(x + (size_t)row * 1024))[tid];
        float ss = xv.x * xv.x + xv.y * xv.y + xv.z * xv.z + xv.w * xv.w;
        #pragma unroll
        for (int m = 32; m; m >>= 1) ss += __shfl_xor(ss, m);
        if ((tid & 63) == 0) red[tid >> 6] = ss;
        __syncthreads();
        const float tot = red[0] + red[1] + red[2] + red[3];
        const float inv = rsqrtf(tot * (1.0f / 1024.0f) + 1.1920928955078125e-07f);
        const float4 gv = ((const float4*)g)[tid];
        ushort4 o;
        o.x = f2bf_bits(xv.x * inv * gv.x);
        o.y = f2bf_bits(xv.y * inv * gv.y);
        o.z = f2bf_bits(xv.z * inv * gv.z);
        o.w = f2bf_bits(xv.w * inv * gv.w);
        *(ushort4*)&xn[gemm_swz(row, tid * 4, 1024)] = o;
        return;
    }
    if (blk >= 2560) {  // rope
        const int idx = (blk - 2560) * 256 + tid;
        const int pos = idx >> 6, i = idx & 63;
        const float theta = powf(10000.0f, -2.0f * (float)(i >> 1) / 64.0f);
        const float ang = (float)pos * theta;
        const float sgn = (pos & 1) ? -1.0f : 1.0f;
        rope[idx] = cosf(ang) + sgn * sinf(ang);
        return;
    }
    // transposes: fp32 [1024][C] -> bf16 [C][1024] (gemm_swz storage)
    const float* src; __hip_bfloat16* dst; int C, i0;
    if (blk < 1024)      { src = w_q; dst = wqkv;                     C = 1024; i0 = blk; }
    else if (blk < 1280) { src = w_k; dst = wqkv + (size_t)1024*1024; C = 256;  i0 = blk - 1024; }
    else if (blk < 1536) { src = w_v; dst = wqkv + (size_t)1280*1024; C = 256;  i0 = blk - 1280; }
    else                 { src = w_o; dst = wo_t;                     C = 1024; i0 = blk - 1536; }
    const int tpr = C >> 5;
    const int c0 = (i0 % tpr) * 32, r0 = (i0 / tpr) * 32;
    const int tx = tid & 31, ty = tid >> 5;
    #pragma unroll
    for (int j = 0; j < 4; j++) {
        int i = ty + j * 8;
        tile[i][tx] = src[(size_t)(r0 + i) * C + c0 + tx];
    }
    __syncthreads();
    #pragma unroll
    for (int j = 0; j < 4; j++) {
        int i = ty + j * 8;
        dst[gemm_swz(c0 + i, r0 + tx, 1024)] = __float2bfloat16(tile[tx][i]);
    }
}

// ------------- GEMM: C = A[M][K] * Bt[N][K]^T, 64x128x32 tiles -------------
// Single-barrier DMA-pipelined K-loop; operands stored gemm_swz.
// MODE 0: QKV epilogue; MODE 1: O epilogue (out = acc + s_in residual)
template <int MODE>
__global__ __launch_bounds__(256, 3) void gemm_kernel(
    const __hip_bfloat16* __restrict__ Abf, const __hip_bfloat16* __restrict__ Bt,
    int M, int N, int K,
    const float* __restrict__ rope,
    __hip_bfloat16* __restrict__ q_bf, __hip_bfloat16* __restrict__ k_bf,
    __hip_bfloat16* __restrict__ vt_bf,
    const __hip_bfloat16* __restrict__ s_in, float* __restrict__ out)
{
    __shared__ __hip_bfloat16 As[2][64 * 32];
    __shared__ __hip_bfloat16 Bs[2][128 * 32];
    const int tid = threadIdx.x;
    const int wv = tid >> 6, lane = tid & 63, quad = lane >> 4, l16 = lane & 15;
    const int m0 = blockIdx.y * 64, n0 = blockIdx.x * 128;
    const int Kt = K >> 5;
    const int rw = lane >> 2, ch = lane & 3;

    f32x4 acc[4][2] = {};

    // prologue DMA tile 0 (A: inst wv; B: insts 2wv, 2wv+1)
    load_lds16(&Abf[(size_t)(m0 + wv * 16 + rw) * K + ch * 8], &As[0][wv * 512]);
    #pragma unroll
    for (int j = 0; j < 2; j++) {
        const int bi = wv * 2 + j;
        load_lds16(&Bt[(size_t)(n0 + bi * 16 + rw) * K + ch * 8], &Bs[0][bi * 512]);
    }

    for (int t = 0; t < Kt; t++) {
        __syncthreads();           // drains DMA(t), issued a full compute phase ago
        if (t + 1 < Kt) {
            const int k0 = (t + 1) * 32, nb = (t + 1) & 1;
            load_lds16(&Abf[(size_t)(m0 + wv * 16 + rw) * K + k0 + ch * 8], &As[nb][wv * 512]);
            #pragma unroll
            for (int j = 0; j < 2; j++) {
                const int bi = wv * 2 + j;
                load_lds16(&Bt[(size_t)(n0 + bi * 16 + rw) * K + k0 + ch * 8], &Bs[nb][bi * 512]);
            }
        }
        const __hip_bfloat16* Ab = As[t & 1];
        const __hip_bfloat16* Bb = Bs[t & 1];
        const int csw = (quad ^ (l16 & 3)) * 8;
        bf16x8 af[4], bfr[2];
        #pragma unroll
        for (int i = 0; i < 4; i++) af[i] = *(const bf16x8*)&Ab[(i * 16 + l16) * 32 + csw];
        #pragma unroll
        for (int n = 0; n < 2; n++) bfr[n] = *(const bf16x8*)&Bb[(wv * 32 + n * 16 + l16) * 32 + csw];
        #pragma unroll
        for (int mt = 0; mt < 4; mt++)
            #pragma unroll
            for (int nt = 0; nt < 2; nt++)
                acc[mt][nt] = MFMA16(af[mt], bfr[nt], acc[mt][nt]);
    }

    #pragma unroll
    for (int mt = 0; mt < 4; mt++) {
        #pragma unroll
        for (int nt = 0; nt < 2; nt++) {
            const int gn = n0 + wv * 32 + nt * 16 + l16;
            #pragma unroll
            for (int r = 0; r < 4; r++) {
                const int m = m0 + mt * 16 + quad * 4 + r;
                float val = acc[mt][nt][r];
                if (MODE == 0) {
                    const int bb = m >> 11, pos = m & 2047;
                    const int a = gn & 63;
                    if (gn < 1024) {
                        const int hh = gn >> 6;
                        val *= rope[pos * 64 + a] * QSCALE;
                        q_bf[((((size_t)bb * 16 + hh) * 2048) + pos) * 64 + a] = __float2bfloat16(val);
                    } else if (gn < 1280) {
                        const int kvh = (gn - 1024) >> 6;
                        val *= rope[pos * 64 + a];
                        k_bf[((size_t)bb * 4 + kvh) * 131072 + k_swz(pos, a)] = __float2bfloat16(val);
                    } else {
                        const int kvh = (gn - 1280) >> 6;
                        vt_bf[((size_t)bb * 4 + kvh) * 131072 + v_swz(pos, a)] = __float2bfloat16(val);
                    }
                } else {
                    out[(size_t)m * N + gn] = val + __bfloat162float(s_in[gemm_swz(m, gn, 1024)]);
                }
            }
        }
    }
}

// ------------- attention: 512-thr block, in-block split-K, barrier-free main loop -------------
// Waves 0-3: keys [0,1024), waves 4-7: keys [1024,2048); each wave 64 q-rows, 32-key tiles.
// P pipelined through wave-private dbuf LDS; partials combined through LDS at the end.
__global__ __launch_bounds__(512, 2) void attn_kernel(
    const __hip_bfloat16* __restrict__ q_bf, const __hip_bfloat16* __restrict__ k_bf,
    const __hip_bfloat16* __restrict__ vt_bf, __hip_bfloat16* __restrict__ s_bf)
{
    __shared__ char smem[81920];   // 8 waves x (2 buf x 64 rows x 40 elems) bf16 P; reused for exchange
    const int tid = threadIdx.x;
    const int wv = tid >> 6, lane = tid & 63, quad = lane >> 4, l16 = lane & 15;
    const int wl = wv & 3, sp = wv >> 2;
    const int qtile = blockIdx.x, bh = blockIdx.y;
    const int b = bh >> 4, h = bh & 15, kvh = h & 3;
    const int q0 = qtile * 256 + wl * 64;

    const __hip_bfloat16* Qp = q_bf + ((((size_t)b * 16 + h) * 2048) + q0) * 64;
    const __hip_bfloat16* Kp = k_bf + ((size_t)b * 4 + kvh) * 131072 + (size_t)sp * 65536 + l16 * 32 + quad * 8;
    const __hip_bfloat16* Vp = vt_bf + ((size_t)b * 4 + kvh) * 131072 + (size_t)sp * 65536 + l16 * 32 + quad * 8;
    __hip_bfloat16* Pw = (__hip_bfloat16*)(smem + wv * 10240);  // [2][64][40]

    // Q fragments: B-operand, 64 q-rows x 64 feats
    bf16x8 bq[4][2];
    #pragma unroll
    for (int qt = 0; qt < 4; qt++)
        #pragma unroll
        for (int ks = 0; ks < 2; ks++)
            bq[qt][ks] = *(const bf16x8*)&Qp[(size_t)(qt * 16 + l16) * 64 + ks * 32 + quad * 8];

    bf16x8 ones;
    #pragma unroll
    for (int i = 0; i < 8; i++) ones[i] = (short)0x3F80;

    bf16x8 ka[2][4], va[4];
    #pragma unroll
    for (int i = 0; i < 4; i++) ka[0][i] = *(const bf16x8*)&Kp[i * 512];

    f32x4 oacc[4][4] = {};   // [feat-tile][q-tile]
    f32x4 lacc[4] = {};

    for (int t = 0; t < 32; t++) {
        // QK^T tile t: S^T[key 32][qrow 64]
        f32x4 sc[2][4] = {};
        #pragma unroll
        for (int ks = 0; ks < 2; ks++)
            #pragma unroll
            for (int nt = 0; nt < 2; nt++)
                #pragma unroll
                for (int qt = 0; qt < 4; qt++)
                    sc[nt][qt] = MFMA16(ka[t & 1][nt * 2 + ks], bq[qt][ks], sc[nt][qt]);
        // V(t-1) fragments (consumed after exp below)
        if (t > 0) {
            #pragma unroll
            for (int i = 0; i < 4; i++)
                va[i] = *(const bf16x8*)&Vp[(size_t)(t - 1) * 2048 + i * 512];
        }
        // K(t+1) prefetch
        if (t < 31) {
            #pragma unroll
            for (int i = 0; i < 4; i++)
                ka[(t + 1) & 1][i] = *(const bf16x8*)&Kp[(size_t)(t + 1) * 2048 + i * 512];
        }
        // exp2 + pack + P write (4 consecutive keys/lane -> b64), dbuf parity t&1
        {
            __hip_bfloat16* P = Pw + (t & 1) * 2560;
            #pragma unroll
            for (int nt = 0; nt < 2; nt++)
                #pragma unroll
                for (int qt = 0; qt < 4; qt++) {
                    const float e0 = __builtin_amdgcn_exp2f(sc[nt][qt][0]);
                    const float e1 = __builtin_amdgcn_exp2f(sc[nt][qt][1]);
                    const float e2 = __builtin_amdgcn_exp2f(sc[nt][qt][2]);
                    const float e3 = __builtin_amdgcn_exp2f(sc[nt][qt][3]);
                    uint2 pk;
                    pk.x = pk_trunc(e0, e1);
                    pk.y = pk_trunc(e2, e3);
                    *(uint2*)&P[(qt * 16 + l16) * 40 + nt * 16 + quad * 4] = pk;
                }
        }
        // PV tile t-1
        if (t > 0) {
            const __hip_bfloat16* P = Pw + ((t & 1) ^ 1) * 2560;
            #pragma unroll
            for (int qt = 0; qt < 4; qt++) {
                bf16x8 bp = *(const bf16x8*)&P[(qt * 16 + l16) * 40 + quad * 8];
                #pragma unroll
                for (int ft = 0; ft < 4; ft++)
                    oacc[ft][qt] = MFMA16(va[ft], bp, oacc[ft][qt]);
                lacc[qt] = MFMA16(ones, bp, lacc[qt]);
            }
        }
    }
    // drain PV tile 31
    #pragma unroll
    for (int i = 0; i < 4; i++)
        va[i] = *(const bf16x8*)&Vp[(size_t)31 * 2048 + i * 512];
    {
        const __hip_bfloat16* P = Pw + 2560;  // parity of t=31
        #pragma unroll
        for (int qt = 0; qt < 4; qt++) {
            bf16x8 bp = *(const bf16x8*)&P[(qt * 16 + l16) * 40 + quad * 8];
            #pragma unroll
            for (int ft = 0; ft < 4; ft++)
                oacc[ft][qt] = MFMA16(va[ft], bp, oacc[ft][qt]);
            lacc[qt] = MFMA16(ones, bp, lacc[qt]);
        }
    }

    // combine split halves through LDS (exchange region aliases P buffers)
    float* exch = (float*)(smem) + wl * 4352;            // [64 rows][68] fp32
    float* lex  = (float*)(smem + 69632) + wl * 64;      // [64] fp32
    __syncthreads();
    if (sp == 1) {
        #pragma unroll
        for (int qt = 0; qt < 4; qt++) {
            #pragma unroll
            for (int ft = 0; ft < 4; ft++)
                *(float4*)&exch[(qt * 16 + l16) * 68 + ft * 16 + quad * 4] = *(const float4*)&oacc[ft][qt];
            if (quad == 0) lex[qt * 16 + l16] = lacc[qt][0];
        }
    }
    __syncthreads();
    if (sp == 0) {
        #pragma unroll
        for (int qt = 0; qt < 4; qt++) {
            const float inv = 1.0f / (lacc[qt][0] + lex[qt * 16 + l16]);
            const int row = (b * 2048) + q0 + qt * 16 + l16;
            #pragma unroll
            for (int ft = 0; ft < 4; ft++) {
                const float4 up = *(const float4*)&exch[(qt * 16 + l16) * 68 + ft * 16 + quad * 4];
                const int feat = h * 64 + ft * 16 + quad * 4;
                ushort4 o;
                o.x = f2bf_bits((oacc[ft][qt][0] + up.x) * inv);
                o.y = f2bf_bits((oacc[ft][qt][1] + up.y) * inv);
                o.z = f2bf_bits((oacc[ft][qt][2] + up.z) * inv);
                o.w = f2bf_bits((oacc[ft][qt][3] + up.w) * inv);
                *(ushort4*)&s_bf[gemm_swz(row, feat, 1024)] = o;
            }
        }
    }
}

extern "C" void kernel_launch(void* const* d_in, const int* in_sizes, int n_in,
                              void* d_out, int out_size, void* d_ws, size_t ws_size,
                              hipStream_t stream)
{
    (void)in_sizes; (void)n_in; (void)out_size; (void)ws_size;
    const float* x   = (const float*)d_in[0];
    const float* w_q = (const float*)d_in[1];
    const float* w_k = (const float*)d_in[2];
    const float* w_v = (const float*)d_in[3];
    const float* w_o = (const float*)d_in[4];
    const float* g   = (const float*)d_in[5];
    float* out = (float*)d_out;

    char* p = (char*)d_ws;
    __hip_bfloat16* xn    = (__hip_bfloat16*)p; p += (size_t)4096 * 1024 * 2;
    __hip_bfloat16* wqkv  = (__hip_bfloat16*)p; p += (size_t)1536 * 1024 * 2;
    __hip_bfloat16* wo_t  = (__hip_bfloat16*)p; p += (size_t)1024 * 1024 * 2;
    float*          rope  = (float*)p;          p += (size_t)2048 * 64 * 4;
    __hip_bfloat16* q_bf  = (__hip_bfloat16*)p; p += (size_t)2 * 16 * 2048 * 64 * 2;
    __hip_bfloat16* k_bf  = (__hip_bfloat16*)p; p += (size_t)2 * 4 * 2048 * 64 * 2;
    __hip_bfloat16* vt_bf = (__hip_bfloat16*)p; p += (size_t)2 * 4 * 64 * 2048 * 2;
    __hip_bfloat16* s_bf  = (__hip_bfloat16*)p; p += (size_t)4096 * 1024 * 2;

    prep_kernel<<<7168, 256, 0, stream>>>(x, w_q, w_k, w_v, w_o, g, xn, wqkv, wo_t, rope);
    gemm_kernel<0><<<dim3(12, 64), 256, 0, stream>>>(xn, wqkv, 4096, 1536, 1024,
                                                     rope, q_bf, k_bf, vt_bf, nullptr, nullptr);
    attn_kernel<<<dim3(8, 32), 512, 0, stream>>>(q_bf, k_bf, vt_bf, s_bf);
    gemm_kernel<1><<<dim3(8, 64), 256, 0, stream>>>(s_bf, wo_t, 4096, 1024, 1024,
                                                    nullptr, nullptr, nullptr, nullptr, s_bf, out);
}

// Round 5
// 176.589 us; speedup vs baseline: 10.7759x; 10.7759x over previous
//
#include <hip/hip_runtime.h>
#include <hip/hip_bf16.h>

typedef short bf16x8 __attribute__((ext_vector_type(8)));
typedef float f32x4 __attribute__((ext_vector_type(4)));

#define MFMA16(a, b, c) __builtin_amdgcn_mfma_f32_16x16x32_bf16((a), (b), (c), 0, 0, 0)

// log2(e)/32 : folded into q so scores feed v_exp_f32 (2^x) directly
#define QSCALE 0.045084220027780106f

static __device__ __forceinline__ unsigned short f2bf_bits(float f) {
    union { float f; unsigned u; } v; v.f = f;
    unsigned u = v.u;
    u += 0x7fff + ((u >> 16) & 1);   // RNE
    return (unsigned short)(u >> 16);
}
// pack two floats' truncated-bf16 into one dword
static __device__ __forceinline__ unsigned pk_trunc(float lo, float hi) {
    union { float f; unsigned u; } a, b; a.f = lo; b.f = hi;
    return __builtin_amdgcn_perm(b.u, a.u, 0x07060302);
}
// async global->LDS, 16B/lane; LDS addr wave-uniform (HW adds lane*16)
static __device__ __forceinline__ void load_lds16(const void* g, void* s) {
    __builtin_amdgcn_global_load_lds(
        (const __attribute__((address_space(1))) unsigned int*)g,
        (__attribute__((address_space(3))) unsigned int*)s, 16, 0, 0);
}
// 2-bit XOR chunk swizzle for GEMM operand storage (per 32-k window)
static __device__ __forceinline__ size_t gemm_swz(int row, int k, int ld) {
    return (size_t)row * ld + (k & ~31) + ((((k >> 3) & 3) ^ (row & 3)) * 8) + (k & 7);
}
// Fragment-order swizzles for 32-key attention tiles (tile = 2048 elems)
static __device__ __forceinline__ size_t k_swz(int key, int feat) {
    return (size_t)(key >> 5) * 2048 + (size_t)(((((key >> 4) & 1) * 2) + (feat >> 5)) * 512)
         + (key & 15) * 32 + ((feat >> 3) & 3) * 8 + (feat & 7);
}
static __device__ __forceinline__ size_t v_swz(int key, int feat) {
    return (size_t)(key >> 5) * 2048 + (size_t)((feat >> 4) * 512)
         + (feat & 15) * 32 + ((key >> 3) & 3) * 8 + (key & 7);
}

// ---------------- fused prep: weight transposes + rope + rmsnorm ----------------
__global__ __launch_bounds__(256) void prep_kernel(
    const float* __restrict__ x, const float* __restrict__ w_q,
    const float* __restrict__ w_k, const float* __restrict__ w_v,
    const float* __restrict__ w_o, const float* __restrict__ g,
    __hip_bfloat16* __restrict__ xn, __hip_bfloat16* __restrict__ wqkv,
    __hip_bfloat16* __restrict__ wo_t, float* __restrict__ rope)
{
    __shared__ float tile[32][33];
    __shared__ float red[4];
    const int blk = blockIdx.x, tid = threadIdx.x;

    if (blk >= 3072) {  // rmsnorm row
        const int row = blk - 3072;
        const float4 xv = ((const float4*)(x + (size_t)row * 1024))[tid];
        float ss = xv.x * xv.x + xv.y * xv.y + xv.z * xv.z + xv.w * xv.w;
        #pragma unroll
        for (int m = 32; m; m >>= 1) ss += __shfl_xor(ss, m);
        if ((tid & 63) == 0) red[tid >> 6] = ss;
        __syncthreads();
        const float tot = red[0] + red[1] + red[2] + red[3];
        const float inv = rsqrtf(tot * (1.0f / 1024.0f) + 1.1920928955078125e-07f);
        const float4 gv = ((const float4*)g)[tid];
        ushort4 o;
        o.x = f2bf_bits(xv.x * inv * gv.x);
        o.y = f2bf_bits(xv.y * inv * gv.y);
        o.z = f2bf_bits(xv.z * inv * gv.z);
        o.w = f2bf_bits(xv.w * inv * gv.w);
        *(ushort4*)&xn[gemm_swz(row, tid * 4, 1024)] = o;
        return;
    }
    if (blk >= 2560) {  // rope
        const int idx = (blk - 2560) * 256 + tid;
        const int pos = idx >> 6, i = idx & 63;
        const float theta = powf(10000.0f, -2.0f * (float)(i >> 1) / 64.0f);
        const float ang = (float)pos * theta;
        const float sgn = (pos & 1) ? -1.0f : 1.0f;
        rope[idx] = cosf(ang) + sgn * sinf(ang);
        return;
    }
    // transposes: fp32 [1024][C] -> bf16 [C][1024] (gemm_swz storage)
    const float* src; __hip_bfloat16* dst; int C, i0;
    if (blk < 1024)      { src = w_q; dst = wqkv;                     C = 1024; i0 = blk; }
    else if (blk < 1280) { src = w_k; dst = wqkv + (size_t)1024*1024; C = 256;  i0 = blk - 1024; }
    else if (blk < 1536) { src = w_v; dst = wqkv + (size_t)1280*1024; C = 256;  i0 = blk - 1280; }
    else                 { src = w_o; dst = wo_t;                     C = 1024; i0 = blk - 1536; }
    const int tpr = C >> 5;
    const int c0 = (i0 % tpr) * 32, r0 = (i0 / tpr) * 32;
    const int tx = tid & 31, ty = tid >> 5;
    #pragma unroll
    for (int j = 0; j < 4; j++) {
        int i = ty + j * 8;
        tile[i][tx] = src[(size_t)(r0 + i) * C + c0 + tx];
    }
    __syncthreads();
    #pragma unroll
    for (int j = 0; j < 4; j++) {
        int i = ty + j * 8;
        dst[gemm_swz(c0 + i, r0 + tx, 1024)] = __float2bfloat16(tile[tx][i]);
    }
}

// ------------- GEMM: C = A[M][K] * Bt[N][K]^T, 64x128x32 tiles -------------
template <int MODE>
__global__ __launch_bounds__(256, 3) void gemm_kernel(
    const __hip_bfloat16* __restrict__ Abf, const __hip_bfloat16* __restrict__ Bt,
    int M, int N, int K,
    const float* __restrict__ rope,
    __hip_bfloat16* __restrict__ q_bf, __hip_bfloat16* __restrict__ k_bf,
    __hip_bfloat16* __restrict__ vt_bf,
    const __hip_bfloat16* __restrict__ s_in, float* __restrict__ out)
{
    __shared__ __hip_bfloat16 As[2][64 * 32];
    __shared__ __hip_bfloat16 Bs[2][128 * 32];
    const int tid = threadIdx.x;
    const int wv = tid >> 6, lane = tid & 63, quad = lane >> 4, l16 = lane & 15;
    const int m0 = blockIdx.y * 64, n0 = blockIdx.x * 128;
    const int Kt = K >> 5;
    const int rw = lane >> 2, ch = lane & 3;

    f32x4 acc[4][2] = {};

    load_lds16(&Abf[(size_t)(m0 + wv * 16 + rw) * K + ch * 8], &As[0][wv * 512]);
    #pragma unroll
    for (int j = 0; j < 2; j++) {
        const int bi = wv * 2 + j;
        load_lds16(&Bt[(size_t)(n0 + bi * 16 + rw) * K + ch * 8], &Bs[0][bi * 512]);
    }

    for (int t = 0; t < Kt; t++) {
        __syncthreads();           // drains DMA(t), issued a full compute phase ago
        if (t + 1 < Kt) {
            const int k0 = (t + 1) * 32, nb = (t + 1) & 1;
            load_lds16(&Abf[(size_t)(m0 + wv * 16 + rw) * K + k0 + ch * 8], &As[nb][wv * 512]);
            #pragma unroll
            for (int j = 0; j < 2; j++) {
                const int bi = wv * 2 + j;
                load_lds16(&Bt[(size_t)(n0 + bi * 16 + rw) * K + k0 + ch * 8], &Bs[nb][bi * 512]);
            }
        }
        const __hip_bfloat16* Ab = As[t & 1];
        const __hip_bfloat16* Bb = Bs[t & 1];
        const int csw = (quad ^ (l16 & 3)) * 8;
        bf16x8 af[4], bfr[2];
        #pragma unroll
        for (int i = 0; i < 4; i++) af[i] = *(const bf16x8*)&Ab[(i * 16 + l16) * 32 + csw];
        #pragma unroll
        for (int n = 0; n < 2; n++) bfr[n] = *(const bf16x8*)&Bb[(wv * 32 + n * 16 + l16) * 32 + csw];
        #pragma unroll
        for (int mt = 0; mt < 4; mt++)
            #pragma unroll
            for (int nt = 0; nt < 2; nt++)
                acc[mt][nt] = MFMA16(af[mt], bfr[nt], acc[mt][nt]);
    }

    #pragma unroll
    for (int mt = 0; mt < 4; mt++) {
        #pragma unroll
        for (int nt = 0; nt < 2; nt++) {
            const int gn = n0 + wv * 32 + nt * 16 + l16;
            #pragma unroll
            for (int r = 0; r < 4; r++) {
                const int m = m0 + mt * 16 + quad * 4 + r;
                float val = acc[mt][nt][r];
                if (MODE == 0) {
                    const int bb = m >> 11, pos = m & 2047;
                    const int a = gn & 63;
                    if (gn < 1024) {
                        const int hh = gn >> 6;
                        val *= rope[pos * 64 + a] * QSCALE;
                        q_bf[((((size_t)bb * 16 + hh) * 2048) + pos) * 64 + a] = __float2bfloat16(val);
                    } else if (gn < 1280) {
                        const int kvh = (gn - 1024) >> 6;
                        val *= rope[pos * 64 + a];
                        k_bf[((size_t)bb * 4 + kvh) * 131072 + k_swz(pos, a)] = __float2bfloat16(val);
                    } else {
                        const int kvh = (gn - 1280) >> 6;
                        vt_bf[((size_t)bb * 4 + kvh) * 131072 + v_swz(pos, a)] = __float2bfloat16(val);
                    }
                } else {
                    out[(size_t)m * N + gn] = val + __bfloat162float(s_in[gemm_swz(m, gn, 1024)]);
                }
            }
        }
    }
}

// ------------- attention: 512-thr block, in-block split-K, barrier-free main loop -------------
// Manual 2x unroll: ka0/ka1 + literal P-buffer offsets => NO runtime-indexed register
// arrays (R4's rolled loop demoted them to scratch: 26x regression, MfmaUtil 0.85%).
#define ATTN_STEP(T, KC, KN, PWOFF, PROFF)                                          \
    {                                                                               \
        f32x4 sc[2][4] = {};                                                        \
        _Pragma("unroll") for (int ks = 0; ks < 2; ks++)                            \
            _Pragma("unroll") for (int nt = 0; nt < 2; nt++)                        \
                _Pragma("unroll") for (int qt = 0; qt < 4; qt++)                    \
                    sc[nt][qt] = MFMA16(KC[nt * 2 + ks], bq[qt][ks], sc[nt][qt]);   \
        if ((T) > 0) {                                                              \
            _Pragma("unroll") for (int i = 0; i < 4; i++)                           \
                va[i] = *(const bf16x8*)&Vp[(size_t)((T) - 1) * 2048 + i * 512];    \
        }                                                                           \
        if ((T) < 31) {                                                             \
            _Pragma("unroll") for (int i = 0; i < 4; i++)                           \
                KN[i] = *(const bf16x8*)&Kp[(size_t)((T) + 1) * 2048 + i * 512];    \
        }                                                                           \
        {                                                                           \
            __hip_bfloat16* P = Pw + (PWOFF);                                       \
            _Pragma("unroll") for (int nt = 0; nt < 2; nt++)                        \
                _Pragma("unroll") for (int qt = 0; qt < 4; qt++) {                  \
                    const float e0 = __builtin_amdgcn_exp2f(sc[nt][qt][0]);         \
                    const float e1 = __builtin_amdgcn_exp2f(sc[nt][qt][1]);         \
                    const float e2 = __builtin_amdgcn_exp2f(sc[nt][qt][2]);         \
                    const float e3 = __builtin_amdgcn_exp2f(sc[nt][qt][3]);         \
                    uint2 pk;                                                       \
                    pk.x = pk_trunc(e0, e1);                                        \
                    pk.y = pk_trunc(e2, e3);                                        \
                    *(uint2*)&P[(qt * 16 + l16) * 40 + nt * 16 + quad * 4] = pk;    \
                }                                                                   \
        }                                                                           \
        if ((T) > 0) {                                                              \
            const __hip_bfloat16* P = Pw + (PROFF);                                 \
            _Pragma("unroll") for (int qt = 0; qt < 4; qt++) {                      \
                bf16x8 bp = *(const bf16x8*)&P[(qt * 16 + l16) * 40 + quad * 8];    \
                _Pragma("unroll") for (int ft = 0; ft < 4; ft++)                    \
                    oacc[ft][qt] = MFMA16(va[ft], bp, oacc[ft][qt]);                \
                lacc[qt] = MFMA16(ones, bp, lacc[qt]);                              \
            }                                                                       \
        }                                                                           \
    }

__global__ __launch_bounds__(512, 2) void attn_kernel(
    const __hip_bfloat16* __restrict__ q_bf, const __hip_bfloat16* __restrict__ k_bf,
    const __hip_bfloat16* __restrict__ vt_bf, __hip_bfloat16* __restrict__ s_bf)
{
    __shared__ char smem[81920];   // 8 waves x (2 buf x 64 rows x 40) bf16 P; reused for exchange
    const int tid = threadIdx.x;
    const int wv = tid >> 6, lane = tid & 63, quad = lane >> 4, l16 = lane & 15;
    const int wl = wv & 3, sp = wv >> 2;
    const int qtile = blockIdx.x, bh = blockIdx.y;
    const int b = bh >> 4, h = bh & 15, kvh = h & 3;
    const int q0 = qtile * 256 + wl * 64;

    const __hip_bfloat16* Qp = q_bf + ((((size_t)b * 16 + h) * 2048) + q0) * 64;
    const __hip_bfloat16* Kp = k_bf + ((size_t)b * 4 + kvh) * 131072 + (size_t)sp * 65536 + l16 * 32 + quad * 8;
    const __hip_bfloat16* Vp = vt_bf + ((size_t)b * 4 + kvh) * 131072 + (size_t)sp * 65536 + l16 * 32 + quad * 8;
    __hip_bfloat16* Pw = (__hip_bfloat16*)(smem + wv * 10240);  // [2][64][40]

    bf16x8 bq[4][2];
    #pragma unroll
    for (int qt = 0; qt < 4; qt++)
        #pragma unroll
        for (int ks = 0; ks < 2; ks++)
            bq[qt][ks] = *(const bf16x8*)&Qp[(size_t)(qt * 16 + l16) * 64 + ks * 32 + quad * 8];

    bf16x8 ones;
    #pragma unroll
    for (int i = 0; i < 8; i++) ones[i] = (short)0x3F80;

    bf16x8 ka0[4], ka1[4], va[4];
    #pragma unroll
    for (int i = 0; i < 4; i++) ka0[i] = *(const bf16x8*)&Kp[i * 512];

    f32x4 oacc[4][4] = {};   // [feat-tile][q-tile]
    f32x4 lacc[4] = {};

    for (int tt = 0; tt < 16; tt++) {
        const int t0 = tt * 2;
        ATTN_STEP(t0,     ka0, ka1, 0,    2560)
        ATTN_STEP(t0 + 1, ka1, ka0, 2560, 0)
    }
    // drain PV tile 31 (P parity 1)
    #pragma unroll
    for (int i = 0; i < 4; i++)
        va[i] = *(const bf16x8*)&Vp[(size_t)31 * 2048 + i * 512];
    {
        const __hip_bfloat16* P = Pw + 2560;
        #pragma unroll
        for (int qt = 0; qt < 4; qt++) {
            bf16x8 bp = *(const bf16x8*)&P[(qt * 16 + l16) * 40 + quad * 8];
            #pragma unroll
            for (int ft = 0; ft < 4; ft++)
                oacc[ft][qt] = MFMA16(va[ft], bp, oacc[ft][qt]);
            lacc[qt] = MFMA16(ones, bp, lacc[qt]);
        }
    }

    // combine split halves through LDS (exchange region aliases P buffers)
    float* exch = (float*)(smem) + wl * 4352;            // [64 rows][68] fp32
    float* lex  = (float*)(smem + 69632) + wl * 64;      // [64] fp32
    __syncthreads();
    if (sp == 1) {
        #pragma unroll
        for (int qt = 0; qt < 4; qt++) {
            #pragma unroll
            for (int ft = 0; ft < 4; ft++)
                *(float4*)&exch[(qt * 16 + l16) * 68 + ft * 16 + quad * 4] = *(const float4*)&oacc[ft][qt];
            if (quad == 0) lex[qt * 16 + l16] = lacc[qt][0];
        }
    }
    __syncthreads();
    if (sp == 0) {
        #pragma unroll
        for (int qt = 0; qt < 4; qt++) {
            const float inv = 1.0f / (lacc[qt][0] + lex[qt * 16 + l16]);
            const int row = (b * 2048) + q0 + qt * 16 + l16;
            #pragma unroll
            for (int ft = 0; ft < 4; ft++) {
                const float4 up = *(const float4*)&exch[(qt * 16 + l16) * 68 + ft * 16 + quad * 4];
                const int feat = h * 64 + ft * 16 + quad * 4;
                ushort4 o;
                o.x = f2bf_bits((oacc[ft][qt][0] + up.x) * inv);
                o.y = f2bf_bits((oacc[ft][qt][1] + up.y) * inv);
                o.z = f2bf_bits((oacc[ft][qt][2] + up.z) * inv);
                o.w = f2bf_bits((oacc[ft][qt][3] + up.w) * inv);
                *(ushort4*)&s_bf[gemm_swz(row, feat, 1024)] = o;
            }
        }
    }
}

extern "C" void kernel_launch(void* const* d_in, const int* in_sizes, int n_in,
                              void* d_out, int out_size, void* d_ws, size_t ws_size,
                              hipStream_t stream)
{
    (void)in_sizes; (void)n_in; (void)out_size; (void)ws_size;
    const float* x   = (const float*)d_in[0];
    const float* w_q = (const float*)d_in[1];
    const float* w_k = (const float*)d_in[2];
    const float* w_v = (const float*)d_in[3];
    const float* w_o = (const float*)d_in[4];
    const float* g   = (const float*)d_in[5];
    float* out = (float*)d_out;

    char* p = (char*)d_ws;
    __hip_bfloat16* xn    = (__hip_bfloat16*)p; p += (size_t)4096 * 1024 * 2;
    __hip_bfloat16* wqkv  = (__hip_bfloat16*)p; p += (size_t)1536 * 1024 * 2;
    __hip_bfloat16* wo_t  = (__hip_bfloat16*)p; p += (size_t)1024 * 1024 * 2;
    float*          rope  = (float*)p;          p += (size_t)2048 * 64 * 4;
    __hip_bfloat16* q_bf  = (__hip_bfloat16*)p; p += (size_t)2 * 16 * 2048 * 64 * 2;
    __hip_bfloat16* k_bf  = (__hip_bfloat16*)p; p += (size_t)2 * 4 * 2048 * 64 * 2;
    __hip_bfloat16* vt_bf = (__hip_bfloat16*)p; p += (size_t)2 * 4 * 64 * 2048 * 2;
    __hip_bfloat16* s_bf  = (__hip_bfloat16*)p; p += (size_t)4096 * 1024 * 2;

    prep_kernel<<<7168, 256, 0, stream>>>(x, w_q, w_k, w_v, w_o, g, xn, wqkv, wo_t, rope);
    gemm_kernel<0><<<dim3(12, 64), 256, 0, stream>>>(xn, wqkv, 4096, 1536, 1024,
                                                     rope, q_bf, k_bf, vt_bf, nullptr, nullptr);
    attn_kernel<<<dim3(8, 32), 512, 0, stream>>>(q_bf, k_bf, vt_bf, s_bf);
    gemm_kernel<1><<<dim3(8, 64), 256, 0, stream>>>(s_bf, wo_t, 4096, 1024, 1024,
                                                    nullptr, nullptr, nullptr, nullptr, s_bf, out);
}

// Round 6
// 164.924 us; speedup vs baseline: 11.5381x; 1.0707x over previous
//
#include <hip/hip_runtime.h>
#include <hip/hip_bf16.h>

typedef short bf16x8 __attribute__((ext_vector_type(8)));
typedef float f32x4 __attribute__((ext_vector_type(4)));

#define MFMA16(a, b, c) __builtin_amdgcn_mfma_f32_16x16x32_bf16((a), (b), (c), 0, 0, 0)

// log2(e)/32 : folded into q so scores feed v_exp_f32 (2^x) directly
#define QSCALE 0.045084220027780106f

static __device__ __forceinline__ unsigned short f2bf_bits(float f) {
    union { float f; unsigned u; } v; v.f = f;
    unsigned u = v.u;
    u += 0x7fff + ((u >> 16) & 1);   // RNE
    return (unsigned short)(u >> 16);
}
// pack two floats' truncated-bf16 into one dword
static __device__ __forceinline__ unsigned pk_trunc(float lo, float hi) {
    union { float f; unsigned u; } a, b; a.f = lo; b.f = hi;
    return __builtin_amdgcn_perm(b.u, a.u, 0x07060302);
}
// async global->LDS, 16B/lane; LDS addr wave-uniform (HW adds lane*16)
static __device__ __forceinline__ void load_lds16(const void* g, void* s) {
    __builtin_amdgcn_global_load_lds(
        (const __attribute__((address_space(1))) unsigned int*)g,
        (__attribute__((address_space(3))) unsigned int*)s, 16, 0, 0);
}
// 3-bit XOR chunk swizzle for GEMM operand storage (per 64-k window).
// Frag reads then hit 8 distinct chunk slots across l16 -> free 2-way banking.
static __device__ __forceinline__ size_t gemm_swz(int row, int k, int ld) {
    return (size_t)row * ld + (k & ~63) + ((((k >> 3) & 7) ^ (row & 7)) * 8) + (k & 7);
}
// Fragment-order swizzles for 32-key attention tiles (tile = 2048 elems)
static __device__ __forceinline__ size_t k_swz(int key, int feat) {
    return (size_t)(key >> 5) * 2048 + (size_t)(((((key >> 4) & 1) * 2) + (feat >> 5)) * 512)
         + (key & 15) * 32 + ((feat >> 3) & 3) * 8 + (feat & 7);
}
static __device__ __forceinline__ size_t v_swz(int key, int feat) {
    return (size_t)(key >> 5) * 2048 + (size_t)((feat >> 4) * 512)
         + (feat & 15) * 32 + ((key >> 3) & 3) * 8 + (key & 7);
}

// ---------------- fused prep: weight transposes + rope + rmsnorm ----------------
__global__ __launch_bounds__(256) void prep_kernel(
    const float* __restrict__ x, const float* __restrict__ w_q,
    const float* __restrict__ w_k, const float* __restrict__ w_v,
    const float* __restrict__ w_o, const float* __restrict__ g,
    __hip_bfloat16* __restrict__ xn, __hip_bfloat16* __restrict__ wqkv,
    __hip_bfloat16* __restrict__ wo_t, float* __restrict__ rope)
{
    __shared__ float tile[32][33];
    __shared__ float red[4];
    const int blk = blockIdx.x, tid = threadIdx.x;

    if (blk >= 3072) {  // rmsnorm row
        const int row = blk - 3072;
        const float4 xv = ((const float4*)(x + (size_t)row * 1024))[tid];
        float ss = xv.x * xv.x + xv.y * xv.y + xv.z * xv.z + xv.w * xv.w;
        #pragma unroll
        for (int m = 32; m; m >>= 1) ss += __shfl_xor(ss, m);
        if ((tid & 63) == 0) red[tid >> 6] = ss;
        __syncthreads();
        const float tot = red[0] + red[1] + red[2] + red[3];
        const float inv = rsqrtf(tot * (1.0f / 1024.0f) + 1.1920928955078125e-07f);
        const float4 gv = ((const float4*)g)[tid];
        ushort4 o;
        o.x = f2bf_bits(xv.x * inv * gv.x);
        o.y = f2bf_bits(xv.y * inv * gv.y);
        o.z = f2bf_bits(xv.z * inv * gv.z);
        o.w = f2bf_bits(xv.w * inv * gv.w);
        *(ushort4*)&xn[gemm_swz(row, tid * 4, 1024)] = o;
        return;
    }
    if (blk >= 2560) {  // rope
        const int idx = (blk - 2560) * 256 + tid;
        const int pos = idx >> 6, i = idx & 63;
        const float theta = powf(10000.0f, -2.0f * (float)(i >> 1) / 64.0f);
        const float ang = (float)pos * theta;
        const float sgn = (pos & 1) ? -1.0f : 1.0f;
        rope[idx] = cosf(ang) + sgn * sinf(ang);
        return;
    }
    // transposes: fp32 [1024][C] -> bf16 [C][1024] (gemm_swz storage)
    const float* src; __hip_bfloat16* dst; int C, i0;
    if (blk < 1024)      { src = w_q; dst = wqkv;                     C = 1024; i0 = blk; }
    else if (blk < 1280) { src = w_k; dst = wqkv + (size_t)1024*1024; C = 256;  i0 = blk - 1024; }
    else if (blk < 1536) { src = w_v; dst = wqkv + (size_t)1280*1024; C = 256;  i0 = blk - 1280; }
    else                 { src = w_o; dst = wo_t;                     C = 1024; i0 = blk - 1536; }
    const int tpr = C >> 5;
    const int c0 = (i0 % tpr) * 32, r0 = (i0 / tpr) * 32;
    const int tx = tid & 31, ty = tid >> 5;
    #pragma unroll
    for (int j = 0; j < 4; j++) {
        int i = ty + j * 8;
        tile[i][tx] = src[(size_t)(r0 + i) * C + c0 + tx];
    }
    __syncthreads();
    #pragma unroll
    for (int j = 0; j < 4; j++) {
        int i = ty + j * 8;
        dst[gemm_swz(c0 + i, r0 + tx, 1024)] = __float2bfloat16(tile[tx][i]);
    }
}

// ------------- GEMM: C = A[M][K] * Bt[N][K]^T, 64x128x64 tiles -------------
// BK=64: 16 MFMA + 12 ds_read_b128 per wave-iter gives DMA(t+1) a full
// latency's worth of compute before the barrier drain; 16 barriers total.
template <int MODE>
__global__ __launch_bounds__(256, 3) void gemm_kernel(
    const __hip_bfloat16* __restrict__ Abf, const __hip_bfloat16* __restrict__ Bt,
    int M, int N, int K,
    const float* __restrict__ rope,
    __hip_bfloat16* __restrict__ q_bf, __hip_bfloat16* __restrict__ k_bf,
    __hip_bfloat16* __restrict__ vt_bf,
    const __hip_bfloat16* __restrict__ s_in, float* __restrict__ out)
{
    __shared__ __hip_bfloat16 As[2][64 * 64];    // 8 KB / buf
    __shared__ __hip_bfloat16 Bs[2][128 * 64];   // 16 KB / buf
    const int tid = threadIdx.x;
    const int wv = tid >> 6, lane = tid & 63, quad = lane >> 4, l16 = lane & 15;
    const int m0 = blockIdx.y * 64, n0 = blockIdx.x * 128;
    const int Kt = K >> 6;
    const int rw = lane >> 3, ch = lane & 7;   // 8 rows x 8 chunks per DMA inst

    f32x4 acc[4][2] = {};

    // DMA one K-tile: A rows wv*16+j*8, j<2 ; B rows wv*32+j*8, j<4
    #define GEMM_DMA(BUF, K0)                                                        \
        _Pragma("unroll") for (int j = 0; j < 2; j++)                                \
            load_lds16(&Abf[(size_t)(m0 + wv * 16 + j * 8 + rw) * K + (K0) + ch * 8],\
                       &As[BUF][(wv * 16 + j * 8) * 64]);                            \
        _Pragma("unroll") for (int j = 0; j < 4; j++)                                \
            load_lds16(&Bt[(size_t)(n0 + wv * 32 + j * 8 + rw) * K + (K0) + ch * 8], \
                       &Bs[BUF][(wv * 32 + j * 8) * 64]);

    GEMM_DMA(0, 0)

    for (int t = 0; t < Kt; t++) {
        __syncthreads();           // drains DMA(t), issued a full compute phase ago
        if (t + 1 < Kt) {
            const int nb = (t + 1) & 1, k0 = (t + 1) * 64;
            GEMM_DMA(nb, k0)
        }
        const __hip_bfloat16* Ab = As[t & 1];
        const __hip_bfloat16* Bb = Bs[t & 1];
        #pragma unroll
        for (int ks = 0; ks < 2; ks++) {
            const int pos = ((ks * 4 + quad) ^ (l16 & 7)) * 8;
            bf16x8 af[4], bfr[2];
            #pragma unroll
            for (int i = 0; i < 4; i++) af[i] = *(const bf16x8*)&Ab[(i * 16 + l16) * 64 + pos];
            #pragma unroll
            for (int n = 0; n < 2; n++) bfr[n] = *(const bf16x8*)&Bb[(wv * 32 + n * 16 + l16) * 64 + pos];
            #pragma unroll
            for (int mt = 0; mt < 4; mt++)
                #pragma unroll
                for (int nt = 0; nt < 2; nt++)
                    acc[mt][nt] = MFMA16(af[mt], bfr[nt], acc[mt][nt]);
        }
    }

    #pragma unroll
    for (int mt = 0; mt < 4; mt++) {
        #pragma unroll
        for (int nt = 0; nt < 2; nt++) {
            const int gn = n0 + wv * 32 + nt * 16 + l16;
            #pragma unroll
            for (int r = 0; r < 4; r++) {
                const int m = m0 + mt * 16 + quad * 4 + r;
                float val = acc[mt][nt][r];
                if (MODE == 0) {
                    const int bb = m >> 11, pos = m & 2047;
                    const int a = gn & 63;
                    if (gn < 1024) {
                        const int hh = gn >> 6;
                        val *= rope[pos * 64 + a] * QSCALE;
                        q_bf[((((size_t)bb * 16 + hh) * 2048) + pos) * 64 + a] = __float2bfloat16(val);
                    } else if (gn < 1280) {
                        const int kvh = (gn - 1024) >> 6;
                        val *= rope[pos * 64 + a];
                        k_bf[((size_t)bb * 4 + kvh) * 131072 + k_swz(pos, a)] = __float2bfloat16(val);
                    } else {
                        const int kvh = (gn - 1280) >> 6;
                        vt_bf[((size_t)bb * 4 + kvh) * 131072 + v_swz(pos, a)] = __float2bfloat16(val);
                    }
                } else {
                    out[(size_t)m * N + gn] = val + __bfloat162float(s_in[gemm_swz(m, gn, 1024)]);
                }
            }
        }
    }
}

// ------------- attention: 512-thr block, in-block split-K, barrier-free main loop -------------
// Manual 2x unroll (compile-time register buffers). K AND V both double-buffered
// one full iteration ahead: V(T) loaded at iter T, consumed by PV at iter T+1.
#define ATTN_STEP(T, KC, KN, VC, VN, PWOFF, PROFF)                                  \
    {                                                                               \
        f32x4 sc[2][4] = {};                                                        \
        _Pragma("unroll") for (int ks = 0; ks < 2; ks++)                            \
            _Pragma("unroll") for (int nt = 0; nt < 2; nt++)                        \
                _Pragma("unroll") for (int qt = 0; qt < 4; qt++)                    \
                    sc[nt][qt] = MFMA16(KC[nt * 2 + ks], bq[qt][ks], sc[nt][qt]);   \
        _Pragma("unroll") for (int i = 0; i < 4; i++)                               \
            VN[i] = *(const bf16x8*)&Vp[(size_t)(T) * 2048 + i * 512];              \
        if ((T) < 31) {                                                             \
            _Pragma("unroll") for (int i = 0; i < 4; i++)                           \
                KN[i] = *(const bf16x8*)&Kp[(size_t)((T) + 1) * 2048 + i * 512];    \
        }                                                                           \
        {                                                                           \
            __hip_bfloat16* P = Pw + (PWOFF);                                       \
            _Pragma("unroll") for (int nt = 0; nt < 2; nt++)                        \
                _Pragma("unroll") for (int qt = 0; qt < 4; qt++) {                  \
                    const float e0 = __builtin_amdgcn_exp2f(sc[nt][qt][0]);         \
                    const float e1 = __builtin_amdgcn_exp2f(sc[nt][qt][1]);         \
                    const float e2 = __builtin_amdgcn_exp2f(sc[nt][qt][2]);         \
                    const float e3 = __builtin_amdgcn_exp2f(sc[nt][qt][3]);         \
                    uint2 pk;                                                       \
                    pk.x = pk_trunc(e0, e1);                                        \
                    pk.y = pk_trunc(e2, e3);                                        \
                    *(uint2*)&P[(qt * 16 + l16) * 40 + nt * 16 + quad * 4] = pk;    \
                }                                                                   \
        }                                                                           \
        if ((T) > 0) {                                                              \
            const __hip_bfloat16* P = Pw + (PROFF);                                 \
            _Pragma("unroll") for (int qt = 0; qt < 4; qt++) {                      \
                bf16x8 bp = *(const bf16x8*)&P[(qt * 16 + l16) * 40 + quad * 8];    \
                _Pragma("unroll") for (int ft = 0; ft < 4; ft++)                    \
                    oacc[ft][qt] = MFMA16(VC[ft], bp, oacc[ft][qt]);                \
                lacc[qt] = MFMA16(ones, bp, lacc[qt]);                              \
            }                                                                       \
        }                                                                           \
    }

__global__ __launch_bounds__(512, 2) void attn_kernel(
    const __hip_bfloat16* __restrict__ q_bf, const __hip_bfloat16* __restrict__ k_bf,
    const __hip_bfloat16* __restrict__ vt_bf, __hip_bfloat16* __restrict__ s_bf)
{
    __shared__ char smem[81920];   // 8 waves x (2 buf x 64 rows x 40) bf16 P; reused for exchange
    const int tid = threadIdx.x;
    const int wv = tid >> 6, lane = tid & 63, quad = lane >> 4, l16 = lane & 15;
    const int wl = wv & 3, sp = wv >> 2;
    const int qtile = blockIdx.x, bh = blockIdx.y;
    const int b = bh >> 4, h = bh & 15, kvh = h & 3;
    const int q0 = qtile * 256 + wl * 64;

    const __hip_bfloat16* Qp = q_bf + ((((size_t)b * 16 + h) * 2048) + q0) * 64;
    const __hip_bfloat16* Kp = k_bf + ((size_t)b * 4 + kvh) * 131072 + (size_t)sp * 65536 + l16 * 32 + quad * 8;
    const __hip_bfloat16* Vp = vt_bf + ((size_t)b * 4 + kvh) * 131072 + (size_t)sp * 65536 + l16 * 32 + quad * 8;
    __hip_bfloat16* Pw = (__hip_bfloat16*)(smem + wv * 10240);  // [2][64][40]

    bf16x8 bq[4][2];
    #pragma unroll
    for (int qt = 0; qt < 4; qt++)
        #pragma unroll
        for (int ks = 0; ks < 2; ks++)
            bq[qt][ks] = *(const bf16x8*)&Qp[(size_t)(qt * 16 + l16) * 64 + ks * 32 + quad * 8];

    bf16x8 ones;
    #pragma unroll
    for (int i = 0; i < 8; i++) ones[i] = (short)0x3F80;

    bf16x8 ka0[4], ka1[4], va0[4], va1[4];
    #pragma unroll
    for (int i = 0; i < 4; i++) ka0[i] = *(const bf16x8*)&Kp[i * 512];

    f32x4 oacc[4][4] = {};   // [feat-tile][q-tile]
    f32x4 lacc[4] = {};

    for (int tt = 0; tt < 16; tt++) {
        const int t0 = tt * 2;
        ATTN_STEP(t0,     ka0, ka1, va1, va0, 0,    2560)
        ATTN_STEP(t0 + 1, ka1, ka0, va0, va1, 2560, 0)
    }
    // drain: PV tile 31 (P parity 1, V in va1)
    {
        const __hip_bfloat16* P = Pw + 2560;
        #pragma unroll
        for (int qt = 0; qt < 4; qt++) {
            bf16x8 bp = *(const bf16x8*)&P[(qt * 16 + l16) * 40 + quad * 8];
            #pragma unroll
            for (int ft = 0; ft < 4; ft++)
                oacc[ft][qt] = MFMA16(va1[ft], bp, oacc[ft][qt]);
            lacc[qt] = MFMA16(ones, bp, lacc[qt]);
        }
    }

    // combine split halves through LDS (exchange region aliases P buffers)
    float* exch = (float*)(smem) + wl * 4352;            // [64 rows][68] fp32
    float* lex  = (float*)(smem + 69632) + wl * 64;      // [64] fp32
    __syncthreads();
    if (sp == 1) {
        #pragma unroll
        for (int qt = 0; qt < 4; qt++) {
            #pragma unroll
            for (int ft = 0; ft < 4; ft++)
                *(float4*)&exch[(qt * 16 + l16) * 68 + ft * 16 + quad * 4] = *(const float4*)&oacc[ft][qt];
            if (quad == 0) lex[qt * 16 + l16] = lacc[qt][0];
        }
    }
    __syncthreads();
    if (sp == 0) {
        #pragma unroll
        for (int qt = 0; qt < 4; qt++) {
            const float inv = 1.0f / (lacc[qt][0] + lex[qt * 16 + l16]);
            const int row = (b * 2048) + q0 + qt * 16 + l16;
            #pragma unroll
            for (int ft = 0; ft < 4; ft++) {
                const float4 up = *(const float4*)&exch[(qt * 16 + l16) * 68 + ft * 16 + quad * 4];
                const int feat = h * 64 + ft * 16 + quad * 4;
                ushort4 o;
                o.x = f2bf_bits((oacc[ft][qt][0] + up.x) * inv);
                o.y = f2bf_bits((oacc[ft][qt][1] + up.y) * inv);
                o.z = f2bf_bits((oacc[ft][qt][2] + up.z) * inv);
                o.w = f2bf_bits((oacc[ft][qt][3] + up.w) * inv);
                *(ushort4*)&s_bf[gemm_swz(row, feat, 1024)] = o;
            }
        }
    }
}

extern "C" void kernel_launch(void* const* d_in, const int* in_sizes, int n_in,
                              void* d_out, int out_size, void* d_ws, size_t ws_size,
                              hipStream_t stream)
{
    (void)in_sizes; (void)n_in; (void)out_size; (void)ws_size;
    const float* x   = (const float*)d_in[0];
    const float* w_q = (const float*)d_in[1];
    const float* w_k = (const float*)d_in[2];
    const float* w_v = (const float*)d_in[3];
    const float* w_o = (const float*)d_in[4];
    const float* g   = (const float*)d_in[5];
    float* out = (float*)d_out;

    char* p = (char*)d_ws;
    __hip_bfloat16* xn    = (__hip_bfloat16*)p; p += (size_t)4096 * 1024 * 2;
    __hip_bfloat16* wqkv  = (__hip_bfloat16*)p; p += (size_t)1536 * 1024 * 2;
    __hip_bfloat16* wo_t  = (__hip_bfloat16*)p; p += (size_t)1024 * 1024 * 2;
    float*          rope  = (float*)p;          p += (size_t)2048 * 64 * 4;
    __hip_bfloat16* q_bf  = (__hip_bfloat16*)p; p += (size_t)2 * 16 * 2048 * 64 * 2;
    __hip_bfloat16* k_bf  = (__hip_bfloat16*)p; p += (size_t)2 * 4 * 2048 * 64 * 2;
    __hip_bfloat16* vt_bf = (__hip_bfloat16*)p; p += (size_t)2 * 4 * 64 * 2048 * 2;
    __hip_bfloat16* s_bf  = (__hip_bfloat16*)p; p += (size_t)4096 * 1024 * 2;

    prep_kernel<<<7168, 256, 0, stream>>>(x, w_q, w_k, w_v, w_o, g, xn, wqkv, wo_t, rope);
    gemm_kernel<0><<<dim3(12, 64), 256, 0, stream>>>(xn, wqkv, 4096, 1536, 1024,
                                                     rope, q_bf, k_bf, vt_bf, nullptr, nullptr);
    attn_kernel<<<dim3(8, 32), 512, 0, stream>>>(q_bf, k_bf, vt_bf, s_bf);
    gemm_kernel<1><<<dim3(8, 64), 256, 0, stream>>>(s_bf, wo_t, 4096, 1024, 1024,
                                                    nullptr, nullptr, nullptr, nullptr, s_bf, out);
}